// Round 11
// baseline (344.784 us; speedup 1.0000x reference)
//
#include <hip/hip_runtime.h>

#define DD    2048
#define KK    256
#define NS    256
#define BB    64
#define SPW   2              // samples per wave
#define WPB   4              // waves per block
#define SPB   (SPW * WPB)    // 8 samples per block
#define NG    (NS / SPB)     // 32 blocks per b
#define ROWS  (NS / SPW)     // 128 partial rows per b (one per wave)
#define NBIN  256            // fine-window bins
#define WHALF 0.5f           // window half-width around tEst
#define FSCALE 256.0f        // NBIN / (2*WHALF)
#define CWAVE 32             // candidate slots per wave
#define PSEGW 17             // coarse hist: padded segment width
#define KKC   (WPB * KK)     // coarse crossing target (4 waves duplicate x)

// Map float bits to order-preserving unsigned, and back.
__device__ __forceinline__ uint32_t orderable(float f) {
    uint32_t u = __float_as_uint(f);
    return (u & 0x80000000u) ? ~u : (u | 0x80000000u);
}
__device__ __forceinline__ float inv_orderable(uint32_t u) {
    return (u & 0x80000000u) ? __uint_as_float(u & 0x7FFFFFFFu)
                             : __uint_as_float(~u);
}

// ---- macros (explicit components / static indices: no scratch) ----
#define CRS1(Q, COMP)                                                   \
    { uint32_t bkt = orderable(xv[Q].COMP) >> 20;                       \
      atomicAdd(&coarse[(bkt >> 4) * PSEGW + (bkt & 15u)], 1u); }
#define CRS4(Q) CRS1(Q, x) CRS1(Q, y) CRS1(Q, z) CRS1(Q, w)

#define BIN1(Q, COMP)                                                   \
    { float val = v[Q].COMP;                                            \
      if (val >= lo) {                                                  \
          int r = (int)((val - lo) * FSCALE);                           \
          if (r >= NBIN) ++W; else atomicAdd(&myHist[r], 1u);           \
      } }
#define BIN4(Q) BIN1(Q, x) BIN1(Q, y) BIN1(Q, z) BIN1(Q, w)

#define CLS1(Q, J, COMP)                                                \
    { float val = v[Q].COMP;                                            \
      if (val >= lo) {                                                  \
          int r = (int)((val - lo) * FSCALE);                           \
          if (r > tb) {                                                 \
              cnt##Q += (1u << (8 * (J)));   /* register byte ctr */    \
          } else if (r == tb) {                                         \
              uint32_t jj = atomicAdd(myCandCnt, 1u);                   \
              if (jj < CWAVE) {                                         \
                  myCf[jj] = val;                                       \
                  myCd[jj] = (uint32_t)(((Q) << 8) + lane * 4 + (J));   \
              }                                                         \
          }                                                             \
      } }
#define CLS4(Q) CLS1(Q, 0, x) CLS1(Q, 1, y) CLS1(Q, 2, z) CLS1(Q, 3, w)

// Single fused kernel:
//   phase 1: per-block coarse x-histogram -> window lower edge `lo`
//   phase 2: wave-autonomous fine-window top-K per sample (no barriers)
//   phase 3 (USE_WS=1): write u8 partial rows; LAST block of each b
//            (device-scope atomic counter) reduces all 128 rows -> out.
//   USE_WS=0 fallback: float atomicAdd into out, finalize kernel after.
template <int USE_WS>
__global__ __launch_bounds__(256) void topk_fused_kernel(
    const float* __restrict__ x,
    const float* __restrict__ noise,
    unsigned char* __restrict__ ws,      // [BB][ROWS][DD] u8 partials
    uint32_t* __restrict__ done,         // [BB] arrival counters (zeroed)
    float* __restrict__ out)             // USE_WS=1: final [2][BB][DD]
                                         // USE_WS=0: counts [BB][DD] (zeroed)
{
    const int tid  = threadIdx.x;
    const int bg   = blockIdx.x;
    const int b    = bg >> 5;            // / NG (NG=32)
    const int g    = bg & (NG - 1);
    const int lane = tid & 63;
    const int wid  = tid >> 6;

    __shared__ uint32_t coarse[256 * PSEGW];   // 17 KB, block coarse hist
    __shared__ uint32_t hist[WPB * NBIN];      // 4 KB, per-wave fine hist
    __shared__ float    cand_f[WPB * CWAVE];
    __shared__ uint32_t cand_d[WPB * CWAVE];
    __shared__ uint32_t candCnt[WPB];
    __shared__ uint32_t wsum[4];
    __shared__ float    sh_lo;
    __shared__ uint32_t sh_last;

    uint32_t* myHist    = hist + wid * NBIN;
    float*    myCf      = cand_f + wid * CWAVE;
    uint32_t* myCd      = cand_d + wid * CWAVE;
    uint32_t* myCandCnt = &candCnt[wid];

    // ---- zero LDS ----
    const uint4 z = make_uint4(0u, 0u, 0u, 0u);
    ((uint4*)hist)[tid] = z;
    #pragma unroll
    for (int i = 0; i < PSEGW; ++i) coarse[tid * PSEGW + i] = 0u;
    if (tid < WPB) candCnt[tid] = 0u;

    // ---- x row -> registers: lane's element d = 256q + 4*lane + j ----
    const float4* xr = (const float4*)(x + (size_t)b * DD);
    float4 xv[8];
    #pragma unroll
    for (int q = 0; q < 8; ++q) xv[q] = xr[q * 64 + lane];

    __syncthreads();                            // B0: zeros visible

    // ---- phase 1: block coarse histogram of x (counts x4 waves) ----
    CRS4(0) CRS4(1) CRS4(2) CRS4(3) CRS4(4) CRS4(5) CRS4(6) CRS4(7)
    __syncthreads();                            // B1
    {
        uint32_t h[16], seg = 0;
        #pragma unroll
        for (int i = 0; i < 16; ++i) { h[i] = coarse[tid * PSEGW + i]; seg += h[i]; }
        uint32_t sfx = seg;
        #pragma unroll
        for (int st = 1; st < 64; st <<= 1) {
            uint32_t o = __shfl_down(sfx, (unsigned)st, 64);
            if (lane + st < 64) sfx += o;
        }
        if (lane == 0) wsum[wid] = sfx;
        __syncthreads();                        // B2
        uint32_t hi = 0;
        #pragma unroll
        for (int w = 0; w < 4; ++w) if (w > wid) hi += wsum[w];
        const uint32_t incl  = sfx + hi;
        const uint32_t above = incl - seg;
        if (above < KKC && incl >= KKC) {
            uint32_t c = above;
            #pragma unroll
            for (int i = 15; i >= 0; --i) {
                if (c + h[i] >= KKC) {
                    sh_lo = inv_orderable(((uint32_t)(tid * 16 + i)) << 20) - WHALF;
                    break;
                }
                c += h[i];
            }
        }
    }
    __syncthreads();                            // B3
    const float lo = sh_lo;

    // ---- phase 2: wave-autonomous fine selection ----
    const int s0 = g * SPB + wid * SPW;
    const float4* nbase =
        (const float4*)(noise + ((size_t)b * NS + s0) * DD);

    uint32_t cnt0 = 0, cnt1 = 0, cnt2 = 0, cnt3 = 0,
             cnt4 = 0, cnt5 = 0, cnt6 = 0, cnt7 = 0;

    for (int s = 0; s < SPW; ++s) {
        const float4* nr = nbase + (size_t)s * (DD / 4);
        float4 v[8];
        #pragma unroll
        for (int q = 0; q < 8; ++q) v[q] = nr[q * 64 + lane];
        #pragma unroll
        for (int q = 0; q < 8; ++q) {
            v[q].x = fmaf(v[q].x, 0.05f, xv[q].x);
            v[q].y = fmaf(v[q].y, 0.05f, xv[q].y);
            v[q].z = fmaf(v[q].z, 0.05f, xv[q].z);
            v[q].w = fmaf(v[q].w, 0.05f, xv[q].w);
        }

        uint32_t W = 0;
        BIN4(0) BIN4(1) BIN4(2) BIN4(3) BIN4(4) BIN4(5) BIN4(6) BIN4(7)
        #pragma unroll
        for (int st = 32; st >= 1; st >>= 1)
            W += __shfl_down(W, (unsigned)st, 64);
        W = __shfl(W, 0, 64);

        uint4 hh = *(const uint4*)&myHist[lane * 4];
        const uint32_t h0 = hh.x, h1 = hh.y, h2 = hh.z, h3 = hh.w;
        uint32_t seg = h0 + h1 + h2 + h3;
        uint32_t sfx = seg;
        #pragma unroll
        for (int st = 1; st < 64; st <<= 1) {
            uint32_t o = __shfl_down(sfx, (unsigned)st, 64);
            if (lane + st < 64) sfx += o;
        }
        const uint32_t incl  = sfx + W;
        const uint32_t above = incl - seg;

        bool cross = (above < KK && incl >= KK);
        unsigned long long mask = __ballot(cross);
        int tbl = NBIN + 1; uint32_t Rl = 0;
        if (cross) {
            uint32_t c = above;
            if (c + h3 >= KK)                { tbl = lane * 4 + 3; Rl = KK - c; }
            else if (c + h3 + h2 >= KK)      { tbl = lane * 4 + 2; Rl = KK - c - h3; }
            else if (c + h3 + h2 + h1 >= KK) { tbl = lane * 4 + 1; Rl = KK - c - h3 - h2; }
            else                             { tbl = lane * 4 + 0; Rl = KK - c - h3 - h2 - h1; }
        }
        int srcl = mask ? (__ffsll((long long)mask) - 1) : 0;
        int      tb = __shfl(tbl, srcl, 64);
        uint32_t R  = __shfl(Rl,  srcl, 64);
        if (!mask) { tb = NBIN + 1; R = 0; }

        CLS4(0) CLS4(1) CLS4(2) CLS4(3) CLS4(4) CLS4(5) CLS4(6) CLS4(7)

        uint32_t M = *myCandCnt;
        if (M > CWAVE) M = CWAVE;
        uint32_t win = 0;
        if ((uint32_t)lane < M) {
            float    vv = myCf[lane];
            uint32_t dj = myCd[lane];
            uint32_t r  = 0;
            for (uint32_t i = 0; i < M; ++i) {
                float vi = myCf[i];
                r += (vi > vv) || (vi == vv && myCd[i] < dj);
            }
            win = (r < R);
        }
        unsigned long long wmask = __ballot(win);
        while (wmask) {
            int j = __ffsll((long long)wmask) - 1;
            wmask &= wmask - 1;
            uint32_t dj = myCd[j];               // uniform LDS broadcast
            if (lane == (int)((dj >> 2) & 63u)) {
                uint32_t inc = 1u << (8u * (dj & 3u));
                switch (dj >> 8) {
                    case 0: cnt0 += inc; break;
                    case 1: cnt1 += inc; break;
                    case 2: cnt2 += inc; break;
                    case 3: cnt3 += inc; break;
                    case 4: cnt4 += inc; break;
                    case 5: cnt5 += inc; break;
                    case 6: cnt6 += inc; break;
                    default: cnt7 += inc; break;
                }
            }
        }
        if (lane == 0) *myCandCnt = 0u;
        *(uint4*)&myHist[lane * 4] = z;          // zero own fine bins
    }

    // ---- phase 3 ----
    if (USE_WS) {
        uint32_t* wrow =
            (uint32_t*)(ws + ((size_t)b * ROWS + (size_t)g * WPB + wid) * DD);
        wrow[0 * 64 + lane] = cnt0;
        wrow[1 * 64 + lane] = cnt1;
        wrow[2 * 64 + lane] = cnt2;
        wrow[3 * 64 + lane] = cnt3;
        wrow[4 * 64 + lane] = cnt4;
        wrow[5 * 64 + lane] = cnt5;
        wrow[6 * 64 + lane] = cnt6;
        wrow[7 * 64 + lane] = cnt7;

        __threadfence();                         // release partial rows
        __syncthreads();
        if (tid == 0)
            sh_last = (atomicAdd(&done[b], 1u) == (uint32_t)(NG - 1));
        __syncthreads();
        if (sh_last) {
            __threadfence();                     // acquire all partials of b
            const unsigned char* basep = ws + (size_t)b * ROWS * DD;
            const float inv = 1.0f / 256.0f;
            #pragma unroll
            for (int hh2 = 0; hh2 < 2; ++hh2) {
                const int dq = tid + hh2 * 256;  // 0 .. 511
                const unsigned char* base = basep + (size_t)dq * 4;
                uint32_t s0a = 0, s1a = 0, s2a = 0, s3a = 0;
                #pragma unroll 8
                for (int g2 = 0; g2 < ROWS; ++g2) {
                    uint32_t p = *(const uint32_t*)(base + (size_t)g2 * DD);
                    s0a += p & 0xFFu;         s1a += (p >> 8) & 0xFFu;
                    s2a += (p >> 16) & 0xFFu; s3a += (p >> 24) & 0xFFu;
                }
                float4 t = make_float4(s0a * inv, s1a * inv, s2a * inv, s3a * inv);
                *(float4*)(out + (size_t)b * DD + dq * 4) = t;
                *(float4*)(out + (size_t)(BB * DD) + (size_t)b * DD + dq * 4) =
                    make_float4(1.0f - t.x, 1.0f - t.y, 1.0f - t.z, 1.0f - t.w);
            }
        }
    } else {
        float* rowOut = out + (size_t)b * DD;
        #pragma unroll
        for (int q = 0; q < 8; ++q) {
            uint32_t c;
            switch (q) {
                case 0: c = cnt0; break; case 1: c = cnt1; break;
                case 2: c = cnt2; break; case 3: c = cnt3; break;
                case 4: c = cnt4; break; case 5: c = cnt5; break;
                case 6: c = cnt6; break; default: c = cnt7; break;
            }
            #pragma unroll
            for (int j = 0; j < 4; ++j) {
                uint32_t byt = (c >> (8 * j)) & 0xFFu;
                if (byt) atomicAdd(&rowOut[q * 256 + lane * 4 + j], (float)byt);
            }
        }
    }
}

// Fallback finalize (only when ws is too small): counts -> (topk, 1-topk).
__global__ __launch_bounds__(256) void finalize_kernel(float* __restrict__ out) {
    int i = blockIdx.x * 256 + threadIdx.x;  // 0 .. BB*DD-1
    float t = out[i] * (1.0f / 256.0f);
    out[i] = t;
    out[BB * DD + i] = 1.0f - t;
}

extern "C" void kernel_launch(void* const* d_in, const int* in_sizes, int n_in,
                              void* d_out, int out_size, void* d_ws, size_t ws_size,
                              hipStream_t stream) {
    const float* x     = (const float*)d_in[0];
    const float* noise = (const float*)d_in[1];
    float* out = (float*)d_out;

    const size_t partials = (size_t)BB * ROWS * DD;         // 16 MB of u8
    if (ws_size >= partials + BB * sizeof(uint32_t)) {
        unsigned char* ws8 = (unsigned char*)d_ws;
        uint32_t* done = (uint32_t*)(ws8 + partials);
        hipMemsetAsync(done, 0, BB * sizeof(uint32_t), stream);
        topk_fused_kernel<1><<<BB * NG, 256, 0, stream>>>(x, noise, ws8, done, out);
    } else {
        hipMemsetAsync(out, 0, (size_t)BB * DD * sizeof(float), stream);
        topk_fused_kernel<0><<<BB * NG, 256, 0, stream>>>(x, noise, nullptr, nullptr, out);
        finalize_kernel<<<(BB * DD) / 256, 256, 0, stream>>>(out);
    }
}

// Round 12
// 43.498 us; speedup vs baseline: 7.9264x; 7.9264x over previous
//
#include <hip/hip_runtime.h>

#define DD    2048
#define KK    256
#define NS    256
#define BB    64
#define WPB   4              // waves per block; ONE sample per wave
#define SPB   WPB            // 4 samples per block
#define NG    (NS / SPB)     // 64 blocks per b
#define ROWS  NG             // 64 u8 partial rows per b (one per block)
#define NBIN  256            // fine-window bins
#define WHALF 0.5f           // window half-width around tEst
#define FSCALE 256.0f        // NBIN / (2*WHALF)
#define CWAVE 32             // candidate slots per wave
#define PSEGW 17             // thresh kernel: padded coarse segments

// Map float bits to order-preserving unsigned, and back.
__device__ __forceinline__ uint32_t orderable(float f) {
    uint32_t u = __float_as_uint(f);
    return (u & 0x80000000u) ? ~u : (u | 0x80000000u);
}
__device__ __forceinline__ float inv_orderable(uint32_t u) {
    return (u & 0x80000000u) ? __uint_as_float(u & 0x7FFFFFFFu)
                             : __uint_as_float(~u);
}

// Per-b approximate top-K threshold of x (lower edge of crossing 12-bit
// bucket). One block per b.
__global__ __launch_bounds__(256) void thresh_kernel(
    const float* __restrict__ x, float* __restrict__ tEst)
{
    const int tid  = threadIdx.x;
    const int b    = blockIdx.x;
    const int lane = tid & 63;
    const int wid  = tid >> 6;
    __shared__ uint32_t hist[256 * PSEGW];
    __shared__ uint32_t wsum[4];

    #pragma unroll
    for (int i = 0; i < PSEGW; ++i) hist[tid * PSEGW + i] = 0u;
    __syncthreads();

    const float4* xr = (const float4*)(x + (size_t)b * DD);
    float4 a0 = xr[tid * 2 + 0], a1 = xr[tid * 2 + 1];
    uint32_t u[8];
    u[0] = orderable(a0.x); u[1] = orderable(a0.y);
    u[2] = orderable(a0.z); u[3] = orderable(a0.w);
    u[4] = orderable(a1.x); u[5] = orderable(a1.y);
    u[6] = orderable(a1.z); u[7] = orderable(a1.w);
    #pragma unroll
    for (int e = 0; e < 8; ++e) {
        uint32_t bkt = u[e] >> 20;
        atomicAdd(&hist[(bkt >> 4) * PSEGW + (bkt & 15u)], 1u);
    }
    __syncthreads();

    uint32_t h[16], seg = 0;
    #pragma unroll
    for (int i = 0; i < 16; ++i) { h[i] = hist[tid * PSEGW + i]; seg += h[i]; }
    uint32_t sfx = seg;
    #pragma unroll
    for (int st = 1; st < 64; st <<= 1) {
        uint32_t o = __shfl_down(sfx, (unsigned)st, 64);
        if (lane + st < 64) sfx += o;
    }
    if (lane == 0) wsum[wid] = sfx;
    __syncthreads();
    uint32_t hi = 0;
    #pragma unroll
    for (int w = 0; w < 4; ++w) if (w > wid) hi += wsum[w];
    const uint32_t incl  = sfx + hi;
    const uint32_t above = incl - seg;
    if (above < KK && incl >= KK) {
        uint32_t c = above;
        #pragma unroll
        for (int i = 15; i >= 0; --i) {
            if (c + h[i] >= KK) {
                tEst[b] = inv_orderable(((uint32_t)(tid * 16 + i)) << 20);
                break;
            }
            c += h[i];
        }
    }
}

// ---- macros (explicit components / static indices: no scratch) ----
#define BIN1(Q, COMP)                                                   \
    { float val = v[Q].COMP;                                            \
      if (val >= lo) {                                                  \
          int r = (int)((val - lo) * FSCALE);                           \
          if (r >= NBIN) ++W; else atomicAdd(&myHist[r], 1u);           \
      } }
#define BIN4(Q) BIN1(Q, x) BIN1(Q, y) BIN1(Q, z) BIN1(Q, w)

#define CLS1(Q, J, COMP)                                                \
    { float val = v[Q].COMP;                                            \
      if (val >= lo) {                                                  \
          int r = (int)((val - lo) * FSCALE);                           \
          int d = ((Q) << 8) + lane * 4 + (J);                          \
          if (r > tb) {                                                 \
              atomicAdd(&counts[d], 1u);                                \
          } else if (r == tb) {                                         \
              uint32_t jj = atomicAdd(myCandCnt, 1u);                   \
              if (jj < CWAVE) { myCf[jj] = val; myCd[jj] = (uint32_t)d; } \
          }                                                             \
      } }
#define CLS4(Q) CLS1(Q, 0, x) CLS1(Q, 1, y) CLS1(Q, 2, z) CLS1(Q, 3, w)

// One sample per wave, straight-line; block merges 4 samples' counts in LDS
// and writes one u8 partial row. Grid = BB*NG = 4096 blocks (deep queue).
template <int USE_WS>
__global__ __launch_bounds__(256) void topk_wave_kernel(
    const float* __restrict__ x,
    const float* __restrict__ noise,
    const float* __restrict__ tEst,
    unsigned char* __restrict__ ws,      // [BB][ROWS][DD] u8 partials
    float* __restrict__ outCounts)       // [BB][DD] f32 (fallback, pre-zeroed)
{
    const int tid  = threadIdx.x;
    const int bg   = blockIdx.x;
    const int b    = bg >> 6;            // / NG (NG=64)
    const int g    = bg & (NG - 1);
    const int lane = tid & 63;
    const int wid  = tid >> 6;

    __shared__ uint32_t counts[DD];            // 8 KB, shared by 4 waves
    __shared__ uint32_t hist[WPB * NBIN];      // 4 KB, per-wave private
    __shared__ float    cand_f[WPB * CWAVE];
    __shared__ uint32_t cand_d[WPB * CWAVE];
    __shared__ uint32_t candCnt[WPB];

    uint32_t* myHist    = hist + wid * NBIN;
    float*    myCf      = cand_f + wid * CWAVE;
    uint32_t* myCd      = cand_d + wid * CWAVE;
    uint32_t* myCandCnt = &candCnt[wid];

    // ---- init ----
    const uint4 z = make_uint4(0u, 0u, 0u, 0u);
    uint4* c4 = (uint4*)counts;
    c4[tid] = z; c4[tid + 256] = z;
    ((uint4*)hist)[tid] = z;
    if (tid < WPB) candCnt[tid] = 0u;

    const float lo = tEst[b] - WHALF;

    // ---- x row -> registers: lane's element d = 256q + 4*lane + j ----
    const float4* xr = (const float4*)(x + (size_t)b * DD);
    float4 xv[8];
    #pragma unroll
    for (int q = 0; q < 8; ++q) xv[q] = xr[q * 64 + lane];

    // this wave's single sample: index g*SPB + wid
    const float4* nr =
        (const float4*)(noise + ((size_t)b * NS + (size_t)g * SPB + wid) * DD);

    __syncthreads();                            // init visible to all waves

    // ---- load noise, perturb in place ----
    float4 v[8];
    #pragma unroll
    for (int q = 0; q < 8; ++q) v[q] = nr[q * 64 + lane];
    #pragma unroll
    for (int q = 0; q < 8; ++q) {
        v[q].x = fmaf(v[q].x, 0.05f, xv[q].x);
        v[q].y = fmaf(v[q].y, 0.05f, xv[q].y);
        v[q].z = fmaf(v[q].z, 0.05f, xv[q].z);
        v[q].w = fmaf(v[q].w, 0.05f, xv[q].w);
    }

    // ---- bin in-window; count above-window ----
    uint32_t W = 0;
    BIN4(0) BIN4(1) BIN4(2) BIN4(3) BIN4(4) BIN4(5) BIN4(6) BIN4(7)
    #pragma unroll
    for (int st = 32; st >= 1; st >>= 1)
        W += __shfl_down(W, (unsigned)st, 64);
    W = __shfl(W, 0, 64);

    // ---- wave suffix scan over 256 bins (lane owns 4*lane..+3) ----
    uint4 hh = *(const uint4*)&myHist[lane * 4];
    const uint32_t h0 = hh.x, h1 = hh.y, h2 = hh.z, h3 = hh.w;
    uint32_t seg = h0 + h1 + h2 + h3;
    uint32_t sfx = seg;
    #pragma unroll
    for (int st = 1; st < 64; st <<= 1) {
        uint32_t o = __shfl_down(sfx, (unsigned)st, 64);
        if (lane + st < 64) sfx += o;
    }
    const uint32_t incl  = sfx + W;
    const uint32_t above = incl - seg;

    // ---- crossing bin via ballot ----
    bool cross = (above < KK && incl >= KK);
    unsigned long long mask = __ballot(cross);
    int tbl = NBIN + 1; uint32_t Rl = 0;
    if (cross) {
        uint32_t c = above;
        if (c + h3 >= KK)                { tbl = lane * 4 + 3; Rl = KK - c; }
        else if (c + h3 + h2 >= KK)      { tbl = lane * 4 + 2; Rl = KK - c - h3; }
        else if (c + h3 + h2 + h1 >= KK) { tbl = lane * 4 + 1; Rl = KK - c - h3 - h2; }
        else                             { tbl = lane * 4 + 0; Rl = KK - c - h3 - h2 - h1; }
    }
    int srcl = mask ? (__ffsll((long long)mask) - 1) : 0;
    int      tb = __shfl(tbl, srcl, 64);
    uint32_t R  = __shfl(Rl,  srcl, 64);
    if (!mask) { tb = NBIN + 1; R = 0; }

    // ---- classify: winners -> LDS atomics into shared counts ----
    CLS4(0) CLS4(1) CLS4(2) CLS4(3) CLS4(4) CLS4(5) CLS4(6) CLS4(7)

    // ---- exact rank-select among wave candidates (M <= 32 < 64) ----
    uint32_t M = *myCandCnt;
    if (M > CWAVE) M = CWAVE;
    if ((uint32_t)lane < M) {
        float    vv = myCf[lane];
        uint32_t dj = myCd[lane];
        uint32_t r  = 0;
        for (uint32_t i = 0; i < M; ++i) {
            float vi = myCf[i];
            r += (vi > vv) || (vi == vv && myCd[i] < dj);
        }
        if (r < R) atomicAdd(&counts[dj], 1u);
    }
    __syncthreads();                            // all waves' adds landed

    // ---- write block partial row (u8, values <= 4) ----
    if (USE_WS) {
        uint32_t* w32 = (uint32_t*)(ws + ((size_t)b * ROWS + g) * DD);
        #pragma unroll
        for (int q = 0; q < 2; ++q) {
            uint32_t p = 0;
            #pragma unroll
            for (int e = 0; e < 4; ++e)
                p |= (counts[tid * 8 + q * 4 + e] & 0xFFu) << (8 * e);
            w32[tid * 2 + q] = p;
        }
    } else {
        float* rowOut = outCounts + (size_t)b * DD;
        #pragma unroll
        for (int e = 0; e < 8; ++e) {
            uint32_t c = counts[tid * 8 + e];
            if (c) atomicAdd(&rowOut[tid * 8 + e], (float)c);
        }
    }
}

// Sum ROWS u8 partials per (b,d), normalize, write both output halves.
__global__ __launch_bounds__(256) void reduce_kernel(
    const unsigned char* __restrict__ ws, float* __restrict__ out)
{
    int idx = blockIdx.x * 256 + threadIdx.x;  // 0 .. BB*DD/4-1
    int b   = idx / (DD / 4);
    int dq  = idx - b * (DD / 4);
    const unsigned char* base = ws + (size_t)b * ROWS * DD + (size_t)dq * 4;
    uint32_t s0 = 0, s1 = 0, s2 = 0, s3 = 0;
    #pragma unroll 8
    for (int g = 0; g < ROWS; ++g) {
        uint32_t p = *(const uint32_t*)(base + (size_t)g * DD);
        s0 += p & 0xFFu; s1 += (p >> 8) & 0xFFu;
        s2 += (p >> 16) & 0xFFu; s3 += (p >> 24) & 0xFFu;
    }
    const float inv = 1.0f / 256.0f;
    float4 t = make_float4(s0 * inv, s1 * inv, s2 * inv, s3 * inv);
    *(float4*)(out + (size_t)b * DD + dq * 4) = t;
    *(float4*)(out + (size_t)(BB * DD) + (size_t)b * DD + dq * 4) =
        make_float4(1.0f - t.x, 1.0f - t.y, 1.0f - t.z, 1.0f - t.w);
}

// Fallback finalize (only when ws is too small): counts -> (topk, 1-topk).
__global__ __launch_bounds__(256) void finalize_kernel(float* __restrict__ out) {
    int i = blockIdx.x * 256 + threadIdx.x;  // 0 .. BB*DD-1
    float t = out[i] * (1.0f / 256.0f);
    out[i] = t;
    out[BB * DD + i] = 1.0f - t;
}

extern "C" void kernel_launch(void* const* d_in, const int* in_sizes, int n_in,
                              void* d_out, int out_size, void* d_ws, size_t ws_size,
                              hipStream_t stream) {
    const float* x     = (const float*)d_in[0];
    const float* noise = (const float*)d_in[1];
    float* out = (float*)d_out;

    const size_t partials = (size_t)BB * ROWS * DD;         // 8 MB of u8
    if (ws_size >= partials + BB * sizeof(float)) {
        unsigned char* ws8 = (unsigned char*)d_ws;
        float* tEst = (float*)(ws8 + partials);
        thresh_kernel<<<BB, 256, 0, stream>>>(x, tEst);
        topk_wave_kernel<1><<<BB * NG, 256, 0, stream>>>(x, noise, tEst, ws8, nullptr);
        reduce_kernel<<<(BB * DD / 4) / 256, 256, 0, stream>>>(ws8, out);
    } else {
        float* tEst = (float*)d_ws;                         // needs 256 B
        hipMemsetAsync(out, 0, (size_t)BB * DD * sizeof(float), stream);
        thresh_kernel<<<BB, 256, 0, stream>>>(x, tEst);
        topk_wave_kernel<0><<<BB * NG, 256, 0, stream>>>(x, noise, tEst, nullptr, out);
        finalize_kernel<<<(BB * DD) / 256, 256, 0, stream>>>(out);
    }
}